// Round 1
// baseline (666.477 us; speedup 1.0000x reference)
//
#include <hip/hip_runtime.h>

// Fused AttentionAggregator: B=4096, N=64, F=128, H=8, D=64, HD=512.
// out[b,n,c] = relu(lin[b,n,c] * softmax_n(leakyrelu(att))[b, c/64, n])
// lin = x @ W_lin via fp16 MFMA (fp16 keeps absmax err ~3e-3 << 2.48e-2 threshold).

typedef _Float16 half8 __attribute__((ext_vector_type(8)));
typedef _Float16 half4v __attribute__((ext_vector_type(4)));
typedef float f32x4 __attribute__((ext_vector_type(4)));

static constexpr int NSEQ = 64;
static constexpr int FIN  = 128;
static constexpr int HDIM = 512;   // H*D
static constexpr int NHEAD = 8;
static constexpr int LIN_LD = 520; // fp16 lin LDS row stride (pad 8 halves: stride 260 words -> 4-bank shift/row)
static constexpr int XS_LD  = 136; // fp16 x LDS row stride (68 words -> 4-bank shift/row)

// Prep: W_lin (fp32 [128][512]) -> W_linT fp16 [512][128] (k-contiguous for B-frags);
//       W_att (fp32 [1024][8])  -> Wa_cat fp16 [16][512]: cols 0..7 = W_att[512+k][col] (lin term),
//                                                          cols 8..15 = W_att[k][col-8] (src term).
__global__ __launch_bounds__(256) void prep_kernel(const float* __restrict__ wlin,
                                                   const float* __restrict__ watt,
                                                   _Float16* __restrict__ wlinT,
                                                   _Float16* __restrict__ wacat)
{
    int t = blockIdx.x * 256 + threadIdx.x;
    if (t < HDIM * FIN) {
        int c = t >> 7;          // output col of W_lin (0..511)
        int k = t & 127;         // k (0..127)
        wlinT[t] = (_Float16)wlin[k * HDIM + c];
    }
    if (t < 16 * HDIM) {
        int col = t >> 9;        // 0..15
        int k = t & 511;         // 0..511
        float v = (col < NHEAD) ? watt[(HDIM + k) * NHEAD + col]
                                : watt[k * NHEAD + (col - NHEAD)];
        wacat[t] = (_Float16)v;
    }
}

__global__ __launch_bounds__(256, 2) void fused_kernel(const float* __restrict__ x,
                                                       const _Float16* __restrict__ wlinT,
                                                       const _Float16* __restrict__ wacat,
                                                       const int* __restrict__ mask,
                                                       float* __restrict__ out)
{
    __shared__ _Float16 lin_s[NSEQ * LIN_LD]; // 66560 B; first 17408 B aliased as x-stage
    __shared__ float attbuf[NSEQ * 17];       // 4352 B (pad 17: stride coprime with 32 banks)
    __shared__ float aw_s[NSEQ * NHEAD];      // 2048 B

    const int b    = blockIdx.x;
    const int t    = threadIdx.x;
    const int lane = t & 63;
    const int w    = t >> 6;      // wave 0..3
    const int l15  = lane & 15;
    const int quad = lane >> 4;   // 0..3

    _Float16* xs = lin_s;         // alias: x-stage dead before lin is written

    // ---- Phase A: stage x[b] (fp32 64x128) -> xs fp16 [64][136] ----
    const float4* xb = (const float4*)(x + (size_t)b * (NSEQ * FIN));
    #pragma unroll
    for (int it = 0; it < 8; ++it) {
        int i = it * 256 + t;            // float4 index, 2048 total
        float4 v = xb[i];
        int n = i >> 5;                  // row
        int k = (i & 31) << 2;           // col
        half4v hv;
        hv[0] = (_Float16)v.x; hv[1] = (_Float16)v.y;
        hv[2] = (_Float16)v.z; hv[3] = (_Float16)v.w;
        *(half4v*)(xs + n * XS_LD + k) = hv;
    }
    __syncthreads();

    // ---- Phase B: lin = x @ W_lin, wave w -> cols [128w, 128w+128) ----
    f32x4 acc[4][8];
    #pragma unroll
    for (int mt = 0; mt < 4; ++mt)
        #pragma unroll
        for (int nt = 0; nt < 8; ++nt)
            acc[mt][nt] = (f32x4){0.f, 0.f, 0.f, 0.f};

    const int colbase = w * 128;
    #pragma unroll
    for (int ks = 0; ks < 4; ++ks) {
        const int k0 = ks * 32 + quad * 8;
        half8 bf[8];
        #pragma unroll
        for (int nt = 0; nt < 8; ++nt) {
            int col = colbase + nt * 16 + l15;
            bf[nt] = *(const half8*)(wlinT + col * FIN + k0);  // 16 B contiguous per lane
        }
        #pragma unroll
        for (int mt = 0; mt < 4; ++mt) {
            half8 af = *(const half8*)(xs + (mt * 16 + l15) * XS_LD + k0);
            #pragma unroll
            for (int nt = 0; nt < 8; ++nt)
                acc[mt][nt] = __builtin_amdgcn_mfma_f32_16x16x32_f16(af, bf[nt], acc[mt][nt], 0, 0, 0);
        }
    }
    __syncthreads();  // all waves done reading xs before lin overwrite

    // ---- Phase C: acc (C-layout: col=l15, row=quad*4+i) -> lin_s fp16 ----
    #pragma unroll
    for (int mt = 0; mt < 4; ++mt)
        #pragma unroll
        for (int nt = 0; nt < 8; ++nt)
            #pragma unroll
            for (int i = 0; i < 4; ++i) {
                int row = mt * 16 + quad * 4 + i;
                int col = colbase + nt * 16 + l15;
                lin_s[row * LIN_LD + col] = (_Float16)acc[mt][nt][i];
            }
    __syncthreads();

    // ---- Phase D: att = lin @ Wa_cat (64x512 @ 512x16), wave = mtile ----
    f32x4 acca = (f32x4){0.f, 0.f, 0.f, 0.f};
    #pragma unroll
    for (int ks = 0; ks < 16; ++ks) {
        int k0 = ks * 32 + quad * 8;
        half8 af = *(const half8*)(lin_s + (w * 16 + l15) * LIN_LD + k0);
        half8 bf = *(const half8*)(wacat + l15 * HDIM + k0);
        acca = __builtin_amdgcn_mfma_f32_16x16x32_f16(af, bf, acca, 0, 0, 0);
    }
    #pragma unroll
    for (int i = 0; i < 4; ++i)
        attbuf[(w * 16 + quad * 4 + i) * 17 + l15] = acca[i];
    __syncthreads();

    // ---- Phase E: leakyrelu + mask + softmax over n; wave w does h = w, w+4 ----
    const int mv = mask[b * NSEQ + lane];
    const float pen = (mv == 0) ? -1e9f : 0.0f;
    #pragma unroll
    for (int rep = 0; rep < 2; ++rep) {
        int hh = w + rep * 4;
        float srcv = attbuf[8 + hh];                 // row 0, col 8+h = src @ W_att[:HD]
        float a = attbuf[lane * 17 + hh] + srcv;     // lane = n
        a = (a >= 0.0f) ? a : 0.2f * a;              // leakyrelu(0.2) BEFORE mask
        a += pen;
        float mx = a;
        #pragma unroll
        for (int off = 32; off > 0; off >>= 1)
            mx = fmaxf(mx, __shfl_xor(mx, off, 64));
        float e = __expf(a - mx);
        float s = e;
        #pragma unroll
        for (int off = 32; off > 0; off >>= 1)
            s += __shfl_xor(s, off, 64);
        aw_s[lane * NHEAD + hh] = e / s;
    }
    __syncthreads();

    // ---- Phase F: out = relu(lin * aw), coalesced dwordx4 stores ----
    float4* ob = (float4*)(out + (size_t)b * (NSEQ * HDIM));
    #pragma unroll
    for (int it = 0; it < 32; ++it) {
        int i = it * 256 + t;            // float4 index, 8192 total
        int n = i >> 7;
        int c = (i & 127) << 2;
        float wgt = aw_s[n * NHEAD + (c >> 6)];
        half4v lv = *(const half4v*)(lin_s + n * LIN_LD + c);
        float4 o;
        o.x = fmaxf((float)lv[0] * wgt, 0.0f);
        o.y = fmaxf((float)lv[1] * wgt, 0.0f);
        o.z = fmaxf((float)lv[2] * wgt, 0.0f);
        o.w = fmaxf((float)lv[3] * wgt, 0.0f);
        ob[i] = o;
    }
}

extern "C" void kernel_launch(void* const* d_in, const int* in_sizes, int n_in,
                              void* d_out, int out_size, void* d_ws, size_t ws_size,
                              hipStream_t stream)
{
    const float* x    = (const float*)d_in[0];
    const float* wlin = (const float*)d_in[1];
    const float* watt = (const float*)d_in[2];
    const int*   mask = (const int*)d_in[3];
    float* out = (float*)d_out;

    _Float16* wlinT = (_Float16*)d_ws;             // 65536 halves = 128 KiB
    _Float16* wacat = wlinT + HDIM * FIN;          // 8192 halves = 16 KiB

    const int B = in_sizes[0] / (NSEQ * FIN);      // 4096

    prep_kernel<<<256, 256, 0, stream>>>(wlin, watt, wlinT, wacat);
    fused_kernel<<<B, 256, 0, stream>>>(x, wlinT, wacat, mask, out);
}

// Round 3
// 648.036 us; speedup vs baseline: 1.0285x; 1.0285x over previous
//
#include <hip/hip_runtime.h>

// Fused AttentionAggregator: B=4096, N=64, F=128, H=8, D=64, HD=512.
// out[b,n,c] = relu(lin[b,n,c] * softmax_n(leakyrelu(att))[b, c/64, n])
// lin = x @ W_lin via fp16 MFMA. Operand-swapped MFMA (A=W, B=x) so each lane
// holds 4 consecutive lin cols -> packed b64 LDS writes. 512-thr blocks,
// launch_bounds(512,4) -> 16 waves/CU for cross-block phase overlap.

typedef _Float16 half8 __attribute__((ext_vector_type(8)));
typedef _Float16 half4v __attribute__((ext_vector_type(4)));
typedef float f32x4 __attribute__((ext_vector_type(4)));

static constexpr int NSEQ  = 64;
static constexpr int FIN   = 128;
static constexpr int HDIM  = 512;   // H*D
static constexpr int NHEAD = 8;
static constexpr int LIN_LD = 520;  // halves; 1040 B/row: b128-aligned, 4 words/bank on all patterns
static constexpr int XS_LD  = 136;  // halves; 272 B/row: b128-aligned, 4 words/bank

// Prep: W_lin (fp32 [128][512]) -> W_linT fp16 [512][128] (k-contiguous);
//       W_att (fp32 [1024][8])  -> Wa_cat fp16 [16][512]: cols 0..7 = W_att[512+k][c] (lin term),
//                                                          cols 8..15 = W_att[k][c-8] (src term).
__global__ __launch_bounds__(256) void prep_kernel(const float* __restrict__ wlin,
                                                   const float* __restrict__ watt,
                                                   _Float16* __restrict__ wlinT,
                                                   _Float16* __restrict__ wacat)
{
    int t = blockIdx.x * 256 + threadIdx.x;
    if (t < HDIM * FIN) {
        int c = t >> 7;
        int k = t & 127;
        wlinT[t] = (_Float16)wlin[k * HDIM + c];
    }
    if (t < 16 * HDIM) {
        int col = t >> 9;
        int k = t & 511;
        float v = (col < NHEAD) ? watt[(HDIM + k) * NHEAD + col]
                                : watt[k * NHEAD + (col - NHEAD)];
        wacat[t] = (_Float16)v;
    }
}

__global__ __launch_bounds__(512, 4) void fused_kernel(const float* __restrict__ x,
                                                       const _Float16* __restrict__ wlinT,
                                                       const _Float16* __restrict__ wacat,
                                                       const int* __restrict__ mask,
                                                       float* __restrict__ out)
{
    __shared__ _Float16 lin_s[NSEQ * LIN_LD];     // 66560 B; head aliased as x-stage
    __shared__ float attbuf[2 * NSEQ * 17];       // 8704 B: two k-half partials of lin@Wa_cat
    __shared__ float aw_s[NSEQ * NHEAD];          // 2048 B

    const int b    = blockIdx.x;
    const int t    = threadIdx.x;
    const int lane = t & 63;
    const int w    = t >> 6;       // wave 0..7
    const int l15  = lane & 15;
    const int quad = lane >> 4;    // 0..3

    _Float16* xs = lin_s;          // alias: x-stage dead before lin is written

    // ---- Phase A: stage x[b] (fp32 64x128) -> xs fp16 [64][136] ----
    const f32x4* xb = (const f32x4*)(x + (size_t)b * (NSEQ * FIN));
    #pragma unroll
    for (int it = 0; it < 4; ++it) {
        int i = it * 512 + t;                  // float4 index, 2048 total
        f32x4 v = __builtin_nontemporal_load(&xb[i]);
        int n = i >> 5;
        int k = (i & 31) << 2;
        half4v hv;
        hv[0] = (_Float16)v[0]; hv[1] = (_Float16)v[1];
        hv[2] = (_Float16)v[2]; hv[3] = (_Float16)v[3];
        *(half4v*)(xs + n * XS_LD + k) = hv;
    }
    __syncthreads();

    // ---- Phase B: lin^T-layout GEMM. A = W_linT cols (m), B = x rows (n).
    //      Wave w owns cols [64w, 64w+64). D: row(quad*4+reg)=W-col, col(l15)=x-row.
    f32x4 acc[4][4];
    #pragma unroll
    for (int mt = 0; mt < 4; ++mt)
        #pragma unroll
        for (int nt = 0; nt < 4; ++nt)
            acc[mt][nt] = (f32x4){0.f, 0.f, 0.f, 0.f};

    const int colbase = w * 64;
    #pragma unroll
    for (int ks = 0; ks < 4; ++ks) {
        const int k0 = ks * 32 + quad * 8;
        half8 a[4];
        #pragma unroll
        for (int mt = 0; mt < 4; ++mt)
            a[mt] = *(const half8*)(wlinT + (colbase + mt * 16 + l15) * FIN + k0);
        #pragma unroll
        for (int nt = 0; nt < 4; ++nt) {
            half8 bfr = *(const half8*)(xs + (nt * 16 + l15) * XS_LD + k0);
            #pragma unroll
            for (int mt = 0; mt < 4; ++mt)
                acc[mt][nt] = __builtin_amdgcn_mfma_f32_16x16x32_f16(a[mt], bfr, acc[mt][nt], 0, 0, 0);
        }
    }
    __syncthreads();  // all waves done reading xs

    // ---- Phase C: lane holds 4 consecutive cols per acc -> packed b64 writes ----
    #pragma unroll
    for (int mt = 0; mt < 4; ++mt)
        #pragma unroll
        for (int nt = 0; nt < 4; ++nt) {
            half4v hv;
            #pragma unroll
            for (int i = 0; i < 4; ++i) hv[i] = (_Float16)acc[mt][nt][i];
            *(half4v*)(lin_s + (nt * 16 + l15) * LIN_LD + colbase + mt * 16 + quad * 4) = hv;
        }
    __syncthreads();

    // ---- Phase D: att partials = lin @ Wa_cat. Wave w: row-tile w&3, k-half w>>2 ----
    {
        const int rt = w & 3;
        const int kh = w >> 2;
        f32x4 acca = (f32x4){0.f, 0.f, 0.f, 0.f};
        #pragma unroll
        for (int ks = 0; ks < 8; ++ks) {
            int k0 = kh * 256 + ks * 32 + quad * 8;
            half8 af = *(const half8*)(lin_s + (rt * 16 + l15) * LIN_LD + k0);
            half8 bf = *(const half8*)(wacat + l15 * HDIM + k0);
            acca = __builtin_amdgcn_mfma_f32_16x16x32_f16(af, bf, acca, 0, 0, 0);
        }
        #pragma unroll
        for (int i = 0; i < 4; ++i)
            attbuf[kh * NSEQ * 17 + (rt * 16 + quad * 4 + i) * 17 + l15] = acca[i];
    }
    __syncthreads();

    // ---- Phase E: leakyrelu + mask + softmax over n; wave w -> head w; lane = n ----
    {
        const int mv = mask[b * NSEQ + lane];
        const float pen = (mv == 0) ? -1e9f : 0.0f;
        const int h = w;
        float srcv = attbuf[8 + h] + attbuf[NSEQ * 17 + 8 + h];        // P[0][8+h], both k-halves
        float a = attbuf[lane * 17 + h] + attbuf[NSEQ * 17 + lane * 17 + h] + srcv;
        a = (a >= 0.0f) ? a : 0.2f * a;                                 // leakyrelu BEFORE mask
        a += pen;
        float mx = a;
        #pragma unroll
        for (int off = 32; off > 0; off >>= 1)
            mx = fmaxf(mx, __shfl_xor(mx, off, 64));
        float e = __expf(a - mx);
        float s = e;
        #pragma unroll
        for (int off = 32; off > 0; off >>= 1)
            s += __shfl_xor(s, off, 64);
        aw_s[lane * NHEAD + h] = e / s;
    }
    __syncthreads();

    // ---- Phase F: out = relu(lin * aw), nontemporal dwordx4 stores ----
    f32x4* ob = (f32x4*)(out + (size_t)b * (NSEQ * HDIM));
    #pragma unroll
    for (int it = 0; it < 16; ++it) {
        int i = it * 512 + t;                  // float4 index, 8192 total
        int n = i >> 7;
        int c = (i & 127) << 2;
        float wgt = aw_s[n * NHEAD + (c >> 6)];
        half4v lv = *(const half4v*)(lin_s + n * LIN_LD + c);
        f32x4 o;
        o[0] = fmaxf((float)lv[0] * wgt, 0.0f);
        o[1] = fmaxf((float)lv[1] * wgt, 0.0f);
        o[2] = fmaxf((float)lv[2] * wgt, 0.0f);
        o[3] = fmaxf((float)lv[3] * wgt, 0.0f);
        __builtin_nontemporal_store(o, &ob[i]);
    }
}

extern "C" void kernel_launch(void* const* d_in, const int* in_sizes, int n_in,
                              void* d_out, int out_size, void* d_ws, size_t ws_size,
                              hipStream_t stream)
{
    const float* x    = (const float*)d_in[0];
    const float* wlin = (const float*)d_in[1];
    const float* watt = (const float*)d_in[2];
    const int*   mask = (const int*)d_in[3];
    float* out = (float*)d_out;

    _Float16* wlinT = (_Float16*)d_ws;             // 65536 halves = 128 KiB
    _Float16* wacat = wlinT + HDIM * FIN;          // 8192 halves = 16 KiB

    const int B = in_sizes[0] / (NSEQ * FIN);      // 4096

    prep_kernel<<<256, 256, 0, stream>>>(wlin, watt, wlinT, wacat);
    fused_kernel<<<B, 512, 0, stream>>>(x, wlinT, wacat, mask, out);
}

// Round 4
// 639.356 us; speedup vs baseline: 1.0424x; 1.0136x over previous
//
#include <hip/hip_runtime.h>

// Fused AttentionAggregator: B=4096, N=64, F=128, H=8, D=64, HD=512.
// out[b,n,c] = relu(lin[b,n,c] * softmax_n(leakyrelu(att))[b, c/64, n])
// lin = x @ W_lin via fp16 MFMA (operand-swapped: A=W cols, B=x rows).
// lin stays register-resident: att partials computed by feeding the phase-B
// accumulator (C-layout) directly as the B-operand of mfma_f32_16x16x16_f16
// (C-layout k=quad*4+i, n=l15 == 16x16x16 B-frag layout per 16-col slice).
// No 66 KB lin_s round trip; LDS 39 KB; 4 barriers; barrier-free output phase.

typedef _Float16 half8  __attribute__((ext_vector_type(8)));
typedef _Float16 half4v __attribute__((ext_vector_type(4)));
typedef float    f32x4  __attribute__((ext_vector_type(4)));

static constexpr int NSEQ  = 64;
static constexpr int FIN   = 128;
static constexpr int HDIM  = 512;   // H*D
static constexpr int NHEAD = 8;
static constexpr int XS_LD = 136;   // halves; 272 B/row, b128-aligned, even bank spread

// smem map (byte offsets):
//   [0, 17408)        xs: x[b] fp16 [64][136]           (phases A,B)
//   [0, 32768)        attbuf: [w][n][j] f32 8x64x16     (phase D -> reduction)
//   [0, 34816)        ftile: per-wave [16][68] f32 x 8  (phase F, private slices)
//   [34816, 39168)    att_s: [n][j] f32 64x17           (reduction -> E)
static constexpr int SMEM_BYTES = 39168;

// Prep: W_lin (fp32 [128][512]) -> W_linT fp16 [512][128] (k-contiguous);
//       W_att (fp32 [1024][8])  -> waA fp16 [8192]: A-fragment-ordered Wa_cat.
//       Wa_cat[c][j]: j in [0,8)  = W_att[512+c][j]   (lin term)
//                     j in [8,16) = W_att[c][j-8]     (src term)
//       waA[((w*4+mt)*64 + lane)*4 + i] = Wa_cat[w*64+mt*16+(lane>>4)*4+i][lane&15]
__global__ __launch_bounds__(256) void prep_kernel(const float* __restrict__ wlin,
                                                   const float* __restrict__ watt,
                                                   _Float16* __restrict__ wlinT,
                                                   _Float16* __restrict__ waA)
{
    int t = blockIdx.x * 256 + threadIdx.x;
    if (t < HDIM * FIN) {
        int c = t >> 7;
        int k = t & 127;
        wlinT[t] = (_Float16)wlin[k * HDIM + c];
    }
    if (t < 16 * HDIM) {                 // 8192 waA halves
        int i     = t & 3;
        int lane  = (t >> 2) & 63;
        int slice = t >> 8;              // w*4 + mt, 0..31
        int c = (slice >> 2) * 64 + (slice & 3) * 16 + (lane >> 4) * 4 + i;
        int j = lane & 15;
        float v = (j < NHEAD) ? watt[(HDIM + c) * NHEAD + j]
                              : watt[c * NHEAD + (j - NHEAD)];
        waA[t] = (_Float16)v;
    }
}

__global__ __launch_bounds__(512, 4) void fused_kernel(const float* __restrict__ x,
                                                       const _Float16* __restrict__ wlinT,
                                                       const _Float16* __restrict__ waA,
                                                       const int* __restrict__ mask,
                                                       float* __restrict__ out)
{
    __shared__ char smem[SMEM_BYTES] __attribute__((aligned(16)));
    _Float16* xs     = (_Float16*)smem;
    float*    attbuf = (float*)smem;
    float*    att_s  = (float*)(smem + 34816);

    const int b    = blockIdx.x;
    const int t    = threadIdx.x;
    const int lane = t & 63;
    const int w    = t >> 6;       // wave 0..7 == head
    const int l15  = lane & 15;
    const int quad = lane >> 4;    // 0..3

    const int mv = mask[b * NSEQ + lane];   // prefetch for phase E

    // ---- Phase A: stage x[b] (fp32 64x128) -> xs fp16 [64][136] ----
    const f32x4* xb = (const f32x4*)(x + (size_t)b * (NSEQ * FIN));
    #pragma unroll
    for (int it = 0; it < 4; ++it) {
        int i = it * 512 + t;                  // float4 index, 2048 total
        f32x4 v = __builtin_nontemporal_load(&xb[i]);
        int n = i >> 5;
        int k = (i & 31) << 2;
        half4v hv;
        hv[0] = (_Float16)v[0]; hv[1] = (_Float16)v[1];
        hv[2] = (_Float16)v[2]; hv[3] = (_Float16)v[3];
        *(half4v*)(xs + n * XS_LD + k) = hv;
    }
    __syncthreads();

    // ---- Phase B: lin^T GEMM. A = W_linT cols (m), B = x rows (n).
    //      Wave w owns cols [64w, 64w+64) = head w.
    //      acc[mt][nt] reg i: lin[n = nt*16+l15][c = 64w + mt*16 + quad*4 + i]
    f32x4 acc[4][4];
    #pragma unroll
    for (int mt = 0; mt < 4; ++mt)
        #pragma unroll
        for (int nt = 0; nt < 4; ++nt)
            acc[mt][nt] = (f32x4){0.f, 0.f, 0.f, 0.f};

    const int colbase = w * 64;
    #pragma unroll
    for (int ks = 0; ks < 4; ++ks) {
        const int k0 = ks * 32 + quad * 8;
        half8 a[4];
        #pragma unroll
        for (int mt = 0; mt < 4; ++mt)
            a[mt] = *(const half8*)(wlinT + (colbase + mt * 16 + l15) * FIN + k0);
        #pragma unroll
        for (int nt = 0; nt < 4; ++nt) {
            half8 bfr = *(const half8*)(xs + (nt * 16 + l15) * XS_LD + k0);
            #pragma unroll
            for (int mt = 0; mt < 4; ++mt)
                acc[mt][nt] = __builtin_amdgcn_mfma_f32_16x16x32_f16(a[mt], bfr, acc[mt][nt], 0, 0, 0);
        }
    }
    __syncthreads();  // xs dead; attbuf may alias it

    // ---- Phase D: att partials T[j][n] = sum_c Wa_cat[c][j] * lin[n][c]
    //      over this wave's 64 cols, via 16x16x16 MFMA with B = cvt_f16(acc).
    {
        f32x4 T[4];
        #pragma unroll
        for (int nt = 0; nt < 4; ++nt) T[nt] = (f32x4){0.f, 0.f, 0.f, 0.f};
        #pragma unroll
        for (int mt = 0; mt < 4; ++mt) {
            half4v aF = *(const half4v*)(waA + ((w * 4 + mt) * 64 + lane) * 4);
            #pragma unroll
            for (int nt = 0; nt < 4; ++nt) {
                half4v bF;
                #pragma unroll
                for (int i = 0; i < 4; ++i) bF[i] = (_Float16)acc[mt][nt][i];
                T[nt] = __builtin_amdgcn_mfma_f32_16x16x16f16(aF, bF, T[nt], 0, 0, 0);
            }
        }
        // T[nt] C-layout: row j = quad*4+reg, col n = nt*16+l15 -> attbuf[w][n][j]
        #pragma unroll
        for (int nt = 0; nt < 4; ++nt)
            *(f32x4*)(attbuf + (w * 64 + nt * 16 + l15) * 16 + quad * 4) = T[nt];
    }
    __syncthreads();

    // ---- Reduction: att[n][j] = sum_w attbuf[w][n][j] -> att_s [n][17] ----
    {
        int n  = t >> 3;          // 0..63
        int j0 = (t & 7) * 2;     // 0,2,..,14
        float s0 = 0.f, s1 = 0.f;
        #pragma unroll
        for (int ww = 0; ww < 8; ++ww) {
            const float* p = attbuf + (ww * 64 + n) * 16 + j0;
            s0 += p[0]; s1 += p[1];
        }
        att_s[n * 17 + j0]     = s0;
        att_s[n * 17 + j0 + 1] = s1;
    }
    __syncthreads();

    // ---- Phase E: leakyrelu + mask + softmax over n; wave w -> head w; lane = n ----
    float aw_reg;
    {
        const float pen = (mv == 0) ? -1e9f : 0.0f;
        float a = att_s[lane * 17 + w] + att_s[8 + w];   // lin term + src term (n=0 row)
        a = (a >= 0.0f) ? a : 0.2f * a;                  // leakyrelu BEFORE mask
        a += pen;
        float mx = a;
        #pragma unroll
        for (int off = 32; off > 0; off >>= 1)
            mx = fmaxf(mx, __shfl_xor(mx, off, 64));
        float e = __expf(a - mx);
        float s = e;
        #pragma unroll
        for (int off = 32; off > 0; off >>= 1)
            s += __shfl_xor(s, off, 64);
        aw_reg = e / s;                                  // aw[w][lane]
    }
    // no barrier: ftile aliases attbuf (dead since reduction barrier),
    // att_s region untouched by phase F, ftile slices are wave-private.

    // ---- Phase F: out = relu(lin * aw) from registers, LDS-tile transpose
    //      for coalesced 256 B row segments. Barrier-free.
    {
        float* ft = (float*)smem + w * (16 * 68);        // private 4352 B tile
        float* outb = out + (size_t)b * (NSEQ * HDIM);
        #pragma unroll
        for (int nt = 0; nt < 4; ++nt) {
            float awv = __shfl(aw_reg, nt * 16 + l15, 64);   // aw[w][n], n = nt*16+l15
            #pragma unroll
            for (int mt = 0; mt < 4; ++mt) {
                f32x4 o;
                #pragma unroll
                for (int i = 0; i < 4; ++i)
                    o[i] = fmaxf(acc[mt][nt][i] * awv, 0.0f);
                *(f32x4*)(ft + l15 * 68 + mt * 16 + quad * 4) = o;   // [n_local][c_local]
            }
            #pragma unroll
            for (int s = 0; s < 4; ++s) {
                int r = s * 4 + quad;                    // n_local
                f32x4 v = *(const f32x4*)(ft + r * 68 + l15 * 4);
                int n = nt * 16 + r;
                __builtin_nontemporal_store(v, (f32x4*)(outb + n * HDIM + w * 64 + l15 * 4));
            }
        }
    }
}

extern "C" void kernel_launch(void* const* d_in, const int* in_sizes, int n_in,
                              void* d_out, int out_size, void* d_ws, size_t ws_size,
                              hipStream_t stream)
{
    const float* x    = (const float*)d_in[0];
    const float* wlin = (const float*)d_in[1];
    const float* watt = (const float*)d_in[2];
    const int*   mask = (const int*)d_in[3];
    float* out = (float*)d_out;

    _Float16* wlinT = (_Float16*)d_ws;             // 65536 halves = 128 KiB
    _Float16* waA   = wlinT + HDIM * FIN;          // 8192 halves = 16 KiB

    const int B = in_sizes[0] / (NSEQ * FIN);      // 4096

    prep_kernel<<<256, 256, 0, stream>>>(wlin, watt, wlinT, waA);
    fused_kernel<<<B, 512, 0, stream>>>(x, wlinT, waA, mask, out);
}